// Round 11
// baseline (306.980 us; speedup 1.0000x reference)
//
#include <hip/hip_runtime.h>
#include <hip/hip_bf16.h>

// B=4, N=2048, DIMX=384, DIMQ=48, H=8.
// out_b = sum_h softmax(Q K^T/sqrt(48)) @ U_bh,  U_bh = X_b M_h^T,  M_h = W_rh W_vh.
// ws layout (bytes), with Xw/Wqw/Wkw aliased INSIDE Ow (dead until attn runs):
//   Mw  bf16 [h*384+c][k:384]          @ 0           (2,359,296)
//   Qw  bf16 [bh][i:2048][d:64 pad]    @ 2,359,296   (8,388,608)
//   Kw  bf16 same                      @ 10,747,904  (8,388,608)   (= Qw + 4,194,304 sh)
//   UT  bf16 [bh][jt:32][swz(c,j:64)]  @ 19,136,512  (50,331,648)  (tiled + XOR-swizzled)
//   Ow  bf16 [bh][i:2048][c:384]       @ 69,468,160  (50,331,648)
//     Xw  bf16 [b][j:2048][k:384]      @ 69,468,160  (6,291,456)   } alias Ow
//     Wqw bf16 [384][384]              @ 75,759,616  (294,912)     } (Wkw = Wqw+147,456 sh)
//     Wkw bf16 [384][384]              @ 76,054,528  (294,912)     }
// peak = 119,799,808 B
//
// R8  (WIN 233->155us attn): cache-BW bound; U staged in LDS via global_load_lds.
// R9  (NULL): SM||PV reorder -- compiler already schedules in-region.
// R10 (WIN 310->294): m97 gemm staging + launch fusion 10->7.
// ROUND-15: tail fusion 6->4 launches. stage1 = cvt||prep_m (independent, one grid);
// gemm_fused = gemm<0>||gemm<1> (flat grid, runtime mode); memset KILLED (MODE0
// store writes the d48..63 Q/K pad zeros directly, each covered exactly once).
// attn (R8) and reduce untouched. Side effect: 4 dispatches => tail becomes
// visible in top-5 rocprof counters next round.

typedef short bf16x8 __attribute__((ext_vector_type(8)));
typedef float f32x4 __attribute__((ext_vector_type(4)));
typedef unsigned short ushort_t;
typedef unsigned int uint_t;

#define MFMA16(A, B, C) __builtin_amdgcn_mfma_f32_16x16x32_bf16(A, B, C, 0, 0, 0)

__device__ __forceinline__ ushort_t bits_bf16(float a) {
  __hip_bfloat16 h = __float2bfloat16(a);
  return *reinterpret_cast<ushort_t*>(&h);
}

// ---------- stage1: fp32->bf16 convert (X,Wq,Wk) || prep M_h = W_rh*W_vh ----------
// blocks [0,3360): cvt; blocks [3360,3648): prep_m (decode (d0,k0,h) from flat id).
__global__ __launch_bounds__(256) void stage1_kernel(const float* __restrict__ X,
                                                     const float* __restrict__ Wq,
                                                     const float* __restrict__ Wk,
                                                     const float* __restrict__ Wr,
                                                     const float* __restrict__ Wv,
                                                     ushort_t* __restrict__ Xw,
                                                     ushort_t* __restrict__ Wqw,
                                                     ushort_t* __restrict__ Wkw,
                                                     ushort_t* __restrict__ Mw) {
  __shared__ float As[32][68];
  __shared__ float Bs[32][68];
  const int t = threadIdx.x;
  if (blockIdx.x < 3360) {
    // ---- cvt path ----
    const int idx = blockIdx.x * 256 + t;
    const float* src;
    ushort_t* dst;
    int off;
    if (idx < 786432) {
      src = X; dst = Xw; off = idx;
    } else if (idx < 786432 + 36864) {
      src = Wq; dst = Wqw; off = idx - 786432;
    } else {
      src = Wk; dst = Wkw; off = idx - (786432 + 36864);
    }
    const float4 v = ((const float4*)src)[off];
    ushort4 o;
    o.x = bits_bf16(v.x); o.y = bits_bf16(v.y); o.z = bits_bf16(v.z); o.w = bits_bf16(v.w);
    ((ushort4*)dst)[off] = o;
    return;
  }
  // ---- prep_m path ----
  const int pb = blockIdx.x - 3360;
  const int h  = pb / 36;
  const int rem = pb - h * 36;
  const int d0 = (rem % 6) << 6;
  const int k0 = (rem / 6) << 6;
  const int ty = t >> 4, tx = t & 15;
  float acc[4][4] = {};
  for (int x0 = 0; x0 < 384; x0 += 32) {
#pragma unroll
    for (int rep = 0; rep < 2; ++rep) {
      int idx = t + (rep << 8);
      int row = idx >> 3, kq = (idx & 7) << 2;
      const float4 a = *(const float4*)&Wr[(size_t)(d0 + row) * 3072 + h * 384 + x0 + kq];
      As[kq + 0][row] = a.x; As[kq + 1][row] = a.y; As[kq + 2][row] = a.z; As[kq + 3][row] = a.w;
      int bro = idx >> 4, bc4 = (idx & 15) << 2;
      *(float4*)&Bs[bro][bc4] = *(const float4*)&Wv[(size_t)(h * 384 + x0 + bro) * 384 + k0 + bc4];
    }
    __syncthreads();
#pragma unroll
    for (int kk = 0; kk < 32; ++kk) {
      const float4 av = *(const float4*)&As[kk][ty << 2];
      const float4 bv = *(const float4*)&Bs[kk][tx << 2];
      const float a[4] = {av.x, av.y, av.z, av.w};
      const float b[4] = {bv.x, bv.y, bv.z, bv.w};
#pragma unroll
      for (int r = 0; r < 4; ++r)
#pragma unroll
        for (int c = 0; c < 4; ++c) acc[r][c] = fmaf(a[r], b[c], acc[r][c]);
    }
    __syncthreads();
  }
#pragma unroll
  for (int r = 0; r < 4; ++r)
#pragma unroll
    for (int c = 0; c < 4; ++c)
      Mw[(size_t)(h * 384 + d0 + (ty << 2) + r) * 384 + k0 + (tx << 2) + c] =
          bits_bf16(acc[r][c]);
}

// ---------- fused bf16 MFMA GEMM (m97 staging), both modes in ONE launch ----------
// blocks [0,384):  MODE0: Q/K projection. bz=bid/192 (0:Q,1:K), by=(bid%192)/64,
//                  bx=bid%64. A=Xw, B=Wqw+bz*147456, dst=Qw+bz*4194304.
//                  Store also zeroes the d48..63 pad (replaces memset).
// blocks [384,1920): MODE1: UT. r=bid-384: bz=r/48 (bh), by=(r%48)/3, bx=r%3.
//                  dst = UT tiled+swizzled: elem = (c*64+jo) ^ ((c&7)<<3).
__global__ __launch_bounds__(256) void gemm_fused_kernel(const ushort_t* __restrict__ Xw,
                                                         const ushort_t* __restrict__ Wqw,
                                                         const ushort_t* __restrict__ Mw,
                                                         ushort_t* __restrict__ Qw,
                                                         ushort_t* __restrict__ UT) {
  __shared__ ushort_t As[128 * 32];
  __shared__ ushort_t Bs[128 * 32];
  const int t = threadIdx.x;
  const int w = t >> 6, lane = t & 63, quad = lane >> 4, l16 = lane & 15;
  const int bid = blockIdx.x;
  int mode, bx, by, bz;
  if (bid < 384) {
    mode = 0; bz = bid / 192;
    const int r = bid - bz * 192;
    by = r >> 6; bx = r & 63;
  } else {
    mode = 1;
    const int r = bid - 384;
    bz = r / 48;
    const int q = r - bz * 48;
    by = q / 3; bx = q - by * 3;
  }
  const int m0 = bx << 7;
  const int n0 = by << 7;
  const ushort_t* Ap;
  const ushort_t* Bp;
  if (mode == 0) {
    Ap = Xw;
    Bp = Wqw + (size_t)bz * 147456;
  } else {
    const int h = bz & 7, b = bz >> 3;
    Ap = Mw + (size_t)h * 147456;
    Bp = Xw + (size_t)b * 786432;
  }
  const int wm = (w & 1) << 6, wn = (w >> 1) << 6;
  const int srow = t >> 2, scol = (t & 3) << 3;
  f32x4 acc[4][4] = {};

  for (int k0 = 0; k0 < 384; k0 += 32) {
    __syncthreads();
#pragma unroll
    for (int r = 0; r < 2; ++r) {
      __builtin_amdgcn_global_load_lds(
          (const __attribute__((address_space(1))) void*)&Ap[(size_t)(m0 + r * 64 + srow) * 384 + k0 + scol],
          (__attribute__((address_space(3))) void*)&As[(r * 64 + srow) * 32 + scol], 16, 0, 0);
      __builtin_amdgcn_global_load_lds(
          (const __attribute__((address_space(1))) void*)&Bp[(size_t)(n0 + r * 64 + srow) * 384 + k0 + scol],
          (__attribute__((address_space(3))) void*)&Bs[(r * 64 + srow) * 32 + scol], 16, 0, 0);
    }
    __syncthreads();
    bf16x8 af[4], bfr[4];
#pragma unroll
    for (int x = 0; x < 4; ++x) {
      af[x] = *(const bf16x8*)&As[(wm + x * 16 + l16) * 32 + quad * 8];
      bfr[x] = *(const bf16x8*)&Bs[(wn + x * 16 + l16) * 32 + quad * 8];
    }
#pragma unroll
    for (int ti = 0; ti < 4; ++ti)
#pragma unroll
      for (int tj = 0; tj < 4; ++tj)
        acc[ti][tj] = MFMA16(af[ti], bfr[tj], acc[ti][tj]);
  }

#pragma unroll
  for (int ti = 0; ti < 4; ++ti) {
    const int gm0 = m0 + wm + ti * 16 + quad * 4;
#pragma unroll
    for (int tj = 0; tj < 4; ++tj) {
      const int gn = n0 + wn + tj * 16 + l16;
#pragma unroll
      for (int r = 0; r < 4; ++r) {
        const ushort_t v = bits_bf16(acc[ti][tj][r]);
        if (mode == 0) {
          const int m = gm0 + r, b = m >> 11, i = m & 2047;
          const int h = gn / 48, dd = gn - h * 48;
          ushort_t* row = Qw + (size_t)bz * 4194304 +
                          (size_t)(((b << 3) + h) * 2048 + i) * 64;
          row[dd] = v;
          if (dd < 16) row[48 + dd] = 0;   // d-pad zero (replaces memset)
        } else {
          const int jt = gn >> 6, jo = gn & 63;
          const int c = gm0 + r;
          const int swz = ((c << 6) + jo) ^ ((c & 7) << 3);
          UT[(size_t)bz * 786432 + (size_t)jt * 24576 + swz] = v;
        }
      }
    }
  }
}

// ---------- fused attention: 8-wave / 128-i block, LDS-staged U (R8 verbatim) ----
__global__ __launch_bounds__(512) void attn_pv_kernel(const ushort_t* __restrict__ Qw,
                                                      const ushort_t* __restrict__ Kw,
                                                      const ushort_t* __restrict__ UT,
                                                      __hip_bfloat16* __restrict__ Ow) {
  __shared__ ushort_t Us[2][24576];     // 2 x 48KB U tile (swizzled content, linear copy)
  __shared__ uint_t Ps[2][128 * 44];    // 45 KB
  __shared__ float Lw[4][128];
  __shared__ float Ls[128];

  const int t = threadIdx.x;
  const int w = t >> 6, lane = t & 63, quad = lane >> 4, l16 = lane & 15;
  const int js = w & 3, ih = w >> 2;
  const int bid = blockIdx.x;
  const int h = bid & 7, i0 = ((bid >> 3) & 15) << 7, b = bid >> 7;
  const int bh = (b << 3) + h;

  const ushort_t* Qg = Qw + ((size_t)bh * 2048 + i0 + ih * 64 + l16) * 64 + quad * 8;
  const ushort_t* Kg = Kw + ((size_t)bh * 2048 + js * 16 + l16) * 64 + quad * 8;
  const ushort_t* Ut = UT + (size_t)bh * 786432;

  bf16x8 qf[4][2];
#pragma unroll
  for (int ti = 0; ti < 4; ++ti)
#pragma unroll
    for (int kh = 0; kh < 2; ++kh)
      qf[ti][kh] = *(const bf16x8*)(Qg + (size_t)ti * 16 * 64 + kh * 32);

  f32x4 acc[4][6] = {};
  float lp[4] = {0.f, 0.f, 0.f, 0.f};
  // exp(s/sqrt(48)) = exp2(s * log2(e)/sqrt(48))
  const float c_exp = 0.14433756729740643f * 1.4426950408889634f;
  const int usw = (l16 & 7) << 4;

#define STAGE_U(BUF, JT)                                                               \
  {                                                                                    \
    const ushort_t* gs = Ut + (size_t)(JT) * 24576 + (w << 9) + (lane << 3);           \
    ushort_t* ls = &Us[BUF][(w << 9)];                                                 \
    _Pragma("unroll") for (int r2 = 0; r2 < 6; ++r2)                                   \
        __builtin_amdgcn_global_load_lds(                                              \
            (const __attribute__((address_space(1))) void*)(gs + (r2 << 12)),          \
            (__attribute__((address_space(3))) void*)(ls + (r2 << 12)), 16, 0, 0);     \
  }

  // prologue: K(0) fragments + stage U(0) -> Us[0]
  bf16x8 kf0 = *(const bf16x8*)(Kg);
  bf16x8 kf1 = *(const bf16x8*)(Kg + 32);
  STAGE_U(0, 0)

  int pb = 0;
  for (int jt = 0; jt < 32; ++jt) {
    // ---- scores(jt): S^T for (i-half ih, j-strip js) ----
    uint_t pw[4][2];
#pragma unroll
    for (int ti = 0; ti < 4; ++ti) {
      f32x4 z = {0.f, 0.f, 0.f, 0.f};
      z = MFMA16(kf0, qf[ti][0], z);
      z = MFMA16(kf1, qf[ti][1], z);
      const uint_t r0 = __float_as_uint(__builtin_amdgcn_exp2f(z[0] * c_exp)) + 0x8000u;
      const uint_t r1 = __float_as_uint(__builtin_amdgcn_exp2f(z[1] * c_exp)) + 0x8000u;
      const uint_t r2 = __float_as_uint(__builtin_amdgcn_exp2f(z[2] * c_exp)) + 0x8000u;
      const uint_t r3 = __float_as_uint(__builtin_amdgcn_exp2f(z[3] * c_exp)) + 0x8000u;
      const uint_t p0 = __builtin_amdgcn_perm(r1, r0, 0x07060302u);
      const uint_t p1 = __builtin_amdgcn_perm(r3, r2, 0x07060302u);
      pw[ti][0] = p0;
      pw[ti][1] = p1;
      // l from the STORED (rounded) values so normalization is exact
      lp[ti] += (__uint_as_float(p0 << 16) + __uint_as_float(p0 & 0xffff0000u)) +
                (__uint_as_float(p1 << 16) + __uint_as_float(p1 & 0xffff0000u));
    }
    // ---- write Ps[pb]: rows ih*64 + ti*16 + l16, words js*8 + quad*2 ----
    {
      uint2* p = (uint2*)&Ps[pb][(ih * 64) * 44 + js * 8 + quad * 2];
#pragma unroll
      for (int ti = 0; ti < 4; ++ti)
        *(uint2*)((uint_t*)p + (ti * 16 + l16) * 44) = uint2{pw[ti][0], pw[ti][1]};
    }
    // ---- barrier: Ps visible; U(jt) stage drained (flight ~= full prev iteration) ----
    __builtin_amdgcn_sched_barrier(0);
    asm volatile("s_waitcnt vmcnt(0) lgkmcnt(0)");
    __builtin_amdgcn_s_barrier();
    __builtin_amdgcn_sched_barrier(0);
    // ---- post-barrier: K(jt+1) frags, stage U(jt+1), then PV(jt) from LDS ----
    {
      const int jn = ((jt + 1) & 31);
      kf0 = *(const bf16x8*)(Kg + (size_t)jn * 4096);
      kf1 = *(const bf16x8*)(Kg + (size_t)jn * 4096 + 32);
      STAGE_U(jn & 1, jn)
    }
    // P A-fragments (2-way banks at stride 44)
    bf16x8 pA[4][2];
#pragma unroll
    for (int ti = 0; ti < 4; ++ti)
#pragma unroll
      for (int ks = 0; ks < 2; ++ks)
        pA[ti][ks] = *(const bf16x8*)&Ps[pb][(ih * 64 + ti * 16 + l16) * 44 +
                                             ks * 16 + quad * 4];
    // PV: U fragments from LDS (swizzled; 2-way banks per quad-phase)
    const char* Ub = (const char*)Us[jt & 1];
#pragma unroll
    for (int tc = 0; tc < 6; ++tc) {
      const int c = js * 96 + tc * 16 + l16;
      const int b0 = (c << 7) + (quad << 4);
      const bf16x8 u0 = *(const bf16x8*)(Ub + (b0 ^ usw));
      const bf16x8 u1 = *(const bf16x8*)(Ub + ((b0 + 64) ^ usw));
#pragma unroll
      for (int ti = 0; ti < 4; ++ti) acc[ti][tc] = MFMA16(pA[ti][0], u0, acc[ti][tc]);
#pragma unroll
      for (int ti = 0; ti < 4; ++ti) acc[ti][tc] = MFMA16(pA[ti][1], u1, acc[ti][tc]);
    }
    pb ^= 1;
  }
#undef STAGE_U

  // ---- softmax denominators: reduce over quads, then over the 4 j-strip waves ----
#pragma unroll
  for (int ti = 0; ti < 4; ++ti) {
    lp[ti] += __shfl_xor(lp[ti], 16);
    lp[ti] += __shfl_xor(lp[ti], 32);
  }
  if (lane < 16) {
#pragma unroll
    for (int ti = 0; ti < 4; ++ti) Lw[js][ih * 64 + ti * 16 + lane] = lp[ti];
  }
  __syncthreads();
  if (t < 128) Ls[t] = 1.0f / (Lw[0][t] + Lw[1][t] + Lw[2][t] + Lw[3][t]);
  __syncthreads();

  // ---- epilogue: normalize, store bf16 partial O ----
  __hip_bfloat16* Op = Ow + ((size_t)bh * 2048 + i0 + ih * 64) * 384 + js * 96 + l16;
#pragma unroll
  for (int ti = 0; ti < 4; ++ti)
#pragma unroll
    for (int r = 0; r < 4; ++r) {
      const float inv = Ls[ih * 64 + ti * 16 + quad * 4 + r];
      __hip_bfloat16* op = Op + (size_t)(ti * 16 + quad * 4 + r) * 384;
#pragma unroll
      for (int tc = 0; tc < 6; ++tc) op[tc * 16] = __float2bfloat16(acc[ti][tc][r] * inv);
    }
}

// ---------- reduce 8 heads ----------
__global__ __launch_bounds__(256) void reduce_kernel(const uint_t* __restrict__ OwU,
                                                     float2* __restrict__ out) {
  const int idx = blockIdx.x * 256 + threadIdx.x;
  const int b = idx / 393216;
  const int rem = idx - b * 393216;
  const uint_t* p = OwU + (size_t)b * 8 * 393216 + rem;
  float s0 = 0.f, s1 = 0.f;
#pragma unroll
  for (int h = 0; h < 8; ++h) {
    const uint_t v = p[(size_t)h * 393216];
    s0 += __uint_as_float(v << 16);
    s1 += __uint_as_float(v & 0xffff0000u);
  }
  out[(size_t)b * 393216 + rem] = float2{s0, s1};
}

extern "C" void kernel_launch(void* const* d_in, const int* in_sizes, int n_in,
                              void* d_out, int out_size, void* d_ws, size_t ws_size,
                              hipStream_t stream) {
  const float* X  = (const float*)d_in[0];
  const float* Wq = (const float*)d_in[1];
  const float* Wk = (const float*)d_in[2];
  const float* Wv = (const float*)d_in[3];
  const float* Wr = (const float*)d_in[4];

  char* ws = (char*)d_ws;
  ushort_t* Mw  = (ushort_t*)(ws);
  ushort_t* Qw  = (ushort_t*)(ws + 2359296);     // Kw = Qw + 4,194,304 shorts
  ushort_t* Kw  = (ushort_t*)(ws + 10747904);
  ushort_t* UT  = (ushort_t*)(ws + 19136512);
  __hip_bfloat16* Ow = (__hip_bfloat16*)(ws + 69468160);
  ushort_t* Xw  = (ushort_t*)(ws + 69468160);    // aliases Ow (dead until attn)
  ushort_t* Wqw = (ushort_t*)(ws + 75759616);    // aliases Ow; Wkw = Wqw + 147,456
  ushort_t* Wkw = (ushort_t*)(ws + 76054528);

  stage1_kernel<<<dim3(3648), 256, 0, stream>>>(X, Wq, Wk, Wr, Wv, Xw, Wqw, Wkw, Mw);
  gemm_fused_kernel<<<dim3(1920), 256, 0, stream>>>(Xw, Wqw, Mw, Qw, UT);
  attn_pv_kernel<<<dim3(512), 512, 0, stream>>>(Qw, Kw, UT, Ow);
  reduce_kernel<<<dim3(6144), 256, 0, stream>>>((const uint_t*)Ow, (float2*)d_out);
}

// Round 12
// 290.762 us; speedup vs baseline: 1.0558x; 1.0558x over previous
//
#include <hip/hip_runtime.h>
#include <hip/hip_bf16.h>

// B=4, N=2048, DIMX=384, DIMQ=48, H=8.
// out_b = sum_h softmax(Q K^T/sqrt(48)) @ U_bh,  U_bh = X_b M_h^T,  M_h = W_rh W_vh.
// ws layout (bytes), with Xw/Wqw/Wkw aliased INSIDE Ow (dead until attn runs):
//   Mw  bf16 [h*384+c][k:384]          @ 0           (2,359,296)
//   Qw  bf16 [bh][i:2048][d:64 pad]    @ 2,359,296   (8,388,608)
//   Kw  bf16 same                      @ 10,747,904  (8,388,608)   (= Qw + 4,194,304 sh)
//   UT  bf16 [bh][jt:32][swz(c,j:64)]  @ 19,136,512  (50,331,648)  (tiled + XOR-swizzled)
//   Ow  bf16 [bh][i:2048][c:384]       @ 69,468,160  (50,331,648)
//     Xw  bf16 [b][j:2048][k:384]      @ 69,468,160  (6,291,456)   } alias Ow
//     Wqw bf16 [384][384]              @ 75,759,616  (294,912)     } (Wkw = Wqw+147,456 sh)
//     Wkw bf16 [384][384]              @ 76,054,528  (294,912)     }
// peak = 119,799,808 B
//
// R8  (WIN 233->155us attn): cache-BW bound; U staged in LDS via global_load_lds.
// R9  (NULL): SM||PV reorder -- compiler already schedules in-region.
// R10 (WIN 310->294): m97 gemm staging + launch fusion 10->7.
// R11 (REGRESS 294->307): stage1/gemm mega-fusion -- LDS-capped cvt occupancy +
//      runtime-mode codegen cost > launch-gap savings. Pad-zero fold verified OK.
// ROUND-16: R10 structure verbatim, minus memset (pad zeros written by gemm<0>'s
// epilogue, R11-verified bit-identical). 6 dispatches.

typedef short bf16x8 __attribute__((ext_vector_type(8)));
typedef float f32x4 __attribute__((ext_vector_type(4)));
typedef unsigned short ushort_t;
typedef unsigned int uint_t;

#define MFMA16(A, B, C) __builtin_amdgcn_mfma_f32_16x16x32_bf16(A, B, C, 0, 0, 0)

__device__ __forceinline__ ushort_t bits_bf16(float a) {
  __hip_bfloat16 h = __float2bfloat16(a);
  return *reinterpret_cast<ushort_t*>(&h);
}

// ---------- fp32 -> bf16 convert: X, Wq, Wk in ONE launch (no LDS) ----------
__global__ __launch_bounds__(256) void cvt_all_kernel(const float* __restrict__ X,
                                                      const float* __restrict__ Wq,
                                                      const float* __restrict__ Wk,
                                                      ushort_t* __restrict__ Xw,
                                                      ushort_t* __restrict__ Wqw,
                                                      ushort_t* __restrict__ Wkw) {
  const int idx = blockIdx.x * 256 + threadIdx.x;
  const float* src;
  ushort_t* dst;
  int off;
  if (idx < 786432) {
    src = X; dst = Xw; off = idx;
  } else if (idx < 786432 + 36864) {
    src = Wq; dst = Wqw; off = idx - 786432;
  } else {
    src = Wk; dst = Wkw; off = idx - (786432 + 36864);
  }
  const float4 v = ((const float4*)src)[off];
  ushort4 o;
  o.x = bits_bf16(v.x); o.y = bits_bf16(v.y); o.z = bits_bf16(v.z); o.w = bits_bf16(v.w);
  ((ushort4*)dst)[off] = o;
}

// ---------- M_h = W_rh * W_vh  (fp32 compute, bf16 out; tiny) ----------
__global__ __launch_bounds__(256) void prep_m_kernel(const float* __restrict__ Wr,
                                                     const float* __restrict__ Wv,
                                                     ushort_t* __restrict__ Mw) {
  __shared__ float As[32][68];
  __shared__ float Bs[32][68];
  const int t = threadIdx.x;
  const int d0 = blockIdx.x << 6;
  const int k0 = blockIdx.y << 6;
  const int h  = blockIdx.z;
  const int ty = t >> 4, tx = t & 15;
  float acc[4][4] = {};
  for (int x0 = 0; x0 < 384; x0 += 32) {
#pragma unroll
    for (int rep = 0; rep < 2; ++rep) {
      int idx = t + (rep << 8);
      int row = idx >> 3, kq = (idx & 7) << 2;
      const float4 a = *(const float4*)&Wr[(size_t)(d0 + row) * 3072 + h * 384 + x0 + kq];
      As[kq + 0][row] = a.x; As[kq + 1][row] = a.y; As[kq + 2][row] = a.z; As[kq + 3][row] = a.w;
      int bro = idx >> 4, bc4 = (idx & 15) << 2;
      *(float4*)&Bs[bro][bc4] = *(const float4*)&Wv[(size_t)(h * 384 + x0 + bro) * 384 + k0 + bc4];
    }
    __syncthreads();
#pragma unroll
    for (int kk = 0; kk < 32; ++kk) {
      const float4 av = *(const float4*)&As[kk][ty << 2];
      const float4 bv = *(const float4*)&Bs[kk][tx << 2];
      const float a[4] = {av.x, av.y, av.z, av.w};
      const float b[4] = {bv.x, bv.y, bv.z, bv.w};
#pragma unroll
      for (int r = 0; r < 4; ++r)
#pragma unroll
        for (int c = 0; c < 4; ++c) acc[r][c] = fmaf(a[r], b[c], acc[r][c]);
    }
    __syncthreads();
  }
#pragma unroll
  for (int r = 0; r < 4; ++r)
#pragma unroll
    for (int c = 0; c < 4; ++c)
      Mw[(size_t)(h * 384 + d0 + (ty << 2) + r) * 384 + k0 + (tx << 2) + c] =
          bits_bf16(acc[r][c]);
}

// ---------- unified bf16 MFMA GEMM, m97 pattern (templated modes) ----------
// MODE 0: A=Xw, B=(Wqw|Wkw by blockIdx.z), dst=(Qw|Kw) packed [bh][i][64-pad];
//         store also writes the d48..63 pad zeros (replaces memset, R11-verified).
// MODE 1: A=Mw_h, B=Xw_b (bh=blockIdx.z), dst=UT tiled+swizzled:
//         element index within 48KB tile = (c*64 + jo) ^ ((c&7)<<3)
template <int MODE>
__global__ __launch_bounds__(256) void gemm_kernel(const ushort_t* __restrict__ Aall,
                                                   const ushort_t* __restrict__ Ball,
                                                   ushort_t* __restrict__ dst) {
  __shared__ ushort_t As[128 * 32];
  __shared__ ushort_t Bs[128 * 32];
  const int t = threadIdx.x;
  const int w = t >> 6, lane = t & 63, quad = lane >> 4, l16 = lane & 15;
  const int m0 = blockIdx.x << 7;
  const int n0 = blockIdx.y << 7;
  const ushort_t* Ap;
  const ushort_t* Bp;
  if (MODE == 0) {
    Ap = Aall;
    Bp = Ball + (size_t)blockIdx.z * 147456;   // Wqw or Wkw (adjacent)
  } else {
    const int bh = blockIdx.z, h = bh & 7, b = bh >> 3;
    Ap = Aall + (size_t)h * 384 * 384;
    Bp = Ball + (size_t)b * 2048 * 384;
  }
  const int wm = (w & 1) << 6, wn = (w >> 1) << 6;
  const int srow = t >> 2, scol = (t & 3) << 3;   // staging: row t>>2, 8-short chunk
  f32x4 acc[4][4] = {};

  for (int k0 = 0; k0 < 384; k0 += 32) {
    __syncthreads();   // previous compute done before overwrite
#pragma unroll
    for (int r = 0; r < 2; ++r) {
      __builtin_amdgcn_global_load_lds(
          (const __attribute__((address_space(1))) void*)&Ap[(size_t)(m0 + r * 64 + srow) * 384 + k0 + scol],
          (__attribute__((address_space(3))) void*)&As[(r * 64 + srow) * 32 + scol], 16, 0, 0);
      __builtin_amdgcn_global_load_lds(
          (const __attribute__((address_space(1))) void*)&Bp[(size_t)(n0 + r * 64 + srow) * 384 + k0 + scol],
          (__attribute__((address_space(3))) void*)&Bs[(r * 64 + srow) * 32 + scol], 16, 0, 0);
    }
    __syncthreads();   // drains vmcnt(0): staged tiles visible
    bf16x8 af[4], bfr[4];
#pragma unroll
    for (int x = 0; x < 4; ++x) {
      af[x] = *(const bf16x8*)&As[(wm + x * 16 + l16) * 32 + quad * 8];
      bfr[x] = *(const bf16x8*)&Bs[(wn + x * 16 + l16) * 32 + quad * 8];
    }
#pragma unroll
    for (int ti = 0; ti < 4; ++ti)
#pragma unroll
      for (int tj = 0; tj < 4; ++tj)
        acc[ti][tj] = MFMA16(af[ti], bfr[tj], acc[ti][tj]);
  }

#pragma unroll
  for (int ti = 0; ti < 4; ++ti) {
    const int gm0 = m0 + wm + ti * 16 + quad * 4;
#pragma unroll
    for (int tj = 0; tj < 4; ++tj) {
      const int gn = n0 + wn + tj * 16 + l16;
#pragma unroll
      for (int r = 0; r < 4; ++r) {
        const ushort_t v = bits_bf16(acc[ti][tj][r]);
        if (MODE == 0) {
          const int m = gm0 + r, b = m >> 11, i = m & 2047;
          const int h = gn / 48, dd = gn - h * 48;
          ushort_t* row = dst + (size_t)blockIdx.z * 4194304 +
                          (size_t)(((b << 3) + h) * 2048 + i) * 64;
          row[dd] = v;
          if (dd < 16) row[48 + dd] = 0;   // d-pad zero (replaces memset)
        } else {
          const int jt = gn >> 6, jo = gn & 63;
          const int c = gm0 + r;
          const int swz = ((c << 6) + jo) ^ ((c & 7) << 3);
          dst[(size_t)blockIdx.z * 786432 + (size_t)jt * 24576 + swz] = v;
        }
      }
    }
  }
}

// ---------- fused attention: 8-wave / 128-i block, LDS-staged U (R8 verbatim) ----
// Wave roles: scores: (ih = w>>2, js = w&3) -> i-half x 16-j strip.
//             PV:     (ih = w>>2, cs = w&3) -> i-half x 96-c strip.
// Per jt: [scores->exp->Ps write] BARRIER(vmcnt0+lgkm0) [K(jt+1), stage U(jt+1)
// via global_load_lds (contiguous 48KB), pA reads, PV from LDS U(jt)].
__global__ __launch_bounds__(512) void attn_pv_kernel(const ushort_t* __restrict__ Qw,
                                                      const ushort_t* __restrict__ Kw,
                                                      const ushort_t* __restrict__ UT,
                                                      __hip_bfloat16* __restrict__ Ow) {
  __shared__ ushort_t Us[2][24576];     // 2 x 48KB U tile (swizzled content, linear copy)
  __shared__ uint_t Ps[2][128 * 44];    // 45 KB
  __shared__ float Lw[4][128];
  __shared__ float Ls[128];

  const int t = threadIdx.x;
  const int w = t >> 6, lane = t & 63, quad = lane >> 4, l16 = lane & 15;
  const int js = w & 3, ih = w >> 2;
  const int bid = blockIdx.x;
  const int h = bid & 7, i0 = ((bid >> 3) & 15) << 7, b = bid >> 7;
  const int bh = (b << 3) + h;

  const ushort_t* Qg = Qw + ((size_t)bh * 2048 + i0 + ih * 64 + l16) * 64 + quad * 8;
  const ushort_t* Kg = Kw + ((size_t)bh * 2048 + js * 16 + l16) * 64 + quad * 8;
  const ushort_t* Ut = UT + (size_t)bh * 786432;

  bf16x8 qf[4][2];
#pragma unroll
  for (int ti = 0; ti < 4; ++ti)
#pragma unroll
    for (int kh = 0; kh < 2; ++kh)
      qf[ti][kh] = *(const bf16x8*)(Qg + (size_t)ti * 16 * 64 + kh * 32);

  f32x4 acc[4][6] = {};
  float lp[4] = {0.f, 0.f, 0.f, 0.f};
  // exp(s/sqrt(48)) = exp2(s * log2(e)/sqrt(48))
  const float c_exp = 0.14433756729740643f * 1.4426950408889634f;
  const int usw = (l16 & 7) << 4;

#define STAGE_U(BUF, JT)                                                               \
  {                                                                                    \
    const ushort_t* gs = Ut + (size_t)(JT) * 24576 + (w << 9) + (lane << 3);           \
    ushort_t* ls = &Us[BUF][(w << 9)];                                                 \
    _Pragma("unroll") for (int r2 = 0; r2 < 6; ++r2)                                   \
        __builtin_amdgcn_global_load_lds(                                              \
            (const __attribute__((address_space(1))) void*)(gs + (r2 << 12)),          \
            (__attribute__((address_space(3))) void*)(ls + (r2 << 12)), 16, 0, 0);     \
  }

  // prologue: K(0) fragments + stage U(0) -> Us[0]
  bf16x8 kf0 = *(const bf16x8*)(Kg);
  bf16x8 kf1 = *(const bf16x8*)(Kg + 32);
  STAGE_U(0, 0)

  int pb = 0;
  for (int jt = 0; jt < 32; ++jt) {
    // ---- scores(jt): S^T for (i-half ih, j-strip js) ----
    uint_t pw[4][2];
#pragma unroll
    for (int ti = 0; ti < 4; ++ti) {
      f32x4 z = {0.f, 0.f, 0.f, 0.f};
      z = MFMA16(kf0, qf[ti][0], z);
      z = MFMA16(kf1, qf[ti][1], z);
      const uint_t r0 = __float_as_uint(__builtin_amdgcn_exp2f(z[0] * c_exp)) + 0x8000u;
      const uint_t r1 = __float_as_uint(__builtin_amdgcn_exp2f(z[1] * c_exp)) + 0x8000u;
      const uint_t r2 = __float_as_uint(__builtin_amdgcn_exp2f(z[2] * c_exp)) + 0x8000u;
      const uint_t r3 = __float_as_uint(__builtin_amdgcn_exp2f(z[3] * c_exp)) + 0x8000u;
      const uint_t p0 = __builtin_amdgcn_perm(r1, r0, 0x07060302u);
      const uint_t p1 = __builtin_amdgcn_perm(r3, r2, 0x07060302u);
      pw[ti][0] = p0;
      pw[ti][1] = p1;
      // l from the STORED (rounded) values so normalization is exact
      lp[ti] += (__uint_as_float(p0 << 16) + __uint_as_float(p0 & 0xffff0000u)) +
                (__uint_as_float(p1 << 16) + __uint_as_float(p1 & 0xffff0000u));
    }
    // ---- write Ps[pb]: rows ih*64 + ti*16 + l16, words js*8 + quad*2 ----
    {
      uint2* p = (uint2*)&Ps[pb][(ih * 64) * 44 + js * 8 + quad * 2];
#pragma unroll
      for (int ti = 0; ti < 4; ++ti)
        *(uint2*)((uint_t*)p + (ti * 16 + l16) * 44) = uint2{pw[ti][0], pw[ti][1]};
    }
    // ---- barrier: Ps visible; U(jt) stage drained (flight ~= full prev iteration) ----
    __builtin_amdgcn_sched_barrier(0);
    asm volatile("s_waitcnt vmcnt(0) lgkmcnt(0)");
    __builtin_amdgcn_s_barrier();
    __builtin_amdgcn_sched_barrier(0);
    // ---- post-barrier: K(jt+1) frags, stage U(jt+1), then PV(jt) from LDS ----
    {
      const int jn = ((jt + 1) & 31);
      kf0 = *(const bf16x8*)(Kg + (size_t)jn * 4096);
      kf1 = *(const bf16x8*)(Kg + (size_t)jn * 4096 + 32);
      STAGE_U(jn & 1, jn)
    }
    // P A-fragments (2-way banks at stride 44)
    bf16x8 pA[4][2];
#pragma unroll
    for (int ti = 0; ti < 4; ++ti)
#pragma unroll
      for (int ks = 0; ks < 2; ++ks)
        pA[ti][ks] = *(const bf16x8*)&Ps[pb][(ih * 64 + ti * 16 + l16) * 44 +
                                             ks * 16 + quad * 4];
    // PV: U fragments from LDS (swizzled; 2-way banks per quad-phase)
    const char* Ub = (const char*)Us[jt & 1];
#pragma unroll
    for (int tc = 0; tc < 6; ++tc) {
      const int c = js * 96 + tc * 16 + l16;
      const int b0 = (c << 7) + (quad << 4);
      const bf16x8 u0 = *(const bf16x8*)(Ub + (b0 ^ usw));
      const bf16x8 u1 = *(const bf16x8*)(Ub + ((b0 + 64) ^ usw));
#pragma unroll
      for (int ti = 0; ti < 4; ++ti) acc[ti][tc] = MFMA16(pA[ti][0], u0, acc[ti][tc]);
#pragma unroll
      for (int ti = 0; ti < 4; ++ti) acc[ti][tc] = MFMA16(pA[ti][1], u1, acc[ti][tc]);
    }
    pb ^= 1;
  }
#undef STAGE_U

  // ---- softmax denominators: reduce over quads, then over the 4 j-strip waves ----
#pragma unroll
  for (int ti = 0; ti < 4; ++ti) {
    lp[ti] += __shfl_xor(lp[ti], 16);
    lp[ti] += __shfl_xor(lp[ti], 32);
  }
  if (lane < 16) {
#pragma unroll
    for (int ti = 0; ti < 4; ++ti) Lw[js][ih * 64 + ti * 16 + lane] = lp[ti];
  }
  __syncthreads();
  if (t < 128) Ls[t] = 1.0f / (Lw[0][t] + Lw[1][t] + Lw[2][t] + Lw[3][t]);
  __syncthreads();

  // ---- epilogue: normalize, store bf16 partial O ----
  __hip_bfloat16* Op = Ow + ((size_t)bh * 2048 + i0 + ih * 64) * 384 + js * 96 + l16;
#pragma unroll
  for (int ti = 0; ti < 4; ++ti)
#pragma unroll
    for (int r = 0; r < 4; ++r) {
      const float inv = Ls[ih * 64 + ti * 16 + quad * 4 + r];
      __hip_bfloat16* op = Op + (size_t)(ti * 16 + quad * 4 + r) * 384;
#pragma unroll
      for (int tc = 0; tc < 6; ++tc) op[tc * 16] = __float2bfloat16(acc[ti][tc][r] * inv);
    }
}

// ---------- reduce 8 heads ----------
__global__ __launch_bounds__(256) void reduce_kernel(const uint_t* __restrict__ OwU,
                                                     float2* __restrict__ out) {
  const int idx = blockIdx.x * 256 + threadIdx.x;
  const int b = idx / 393216;
  const int rem = idx - b * 393216;
  const uint_t* p = OwU + (size_t)b * 8 * 393216 + rem;
  float s0 = 0.f, s1 = 0.f;
#pragma unroll
  for (int h = 0; h < 8; ++h) {
    const uint_t v = p[(size_t)h * 393216];
    s0 += __uint_as_float(v << 16);
    s1 += __uint_as_float(v & 0xffff0000u);
  }
  out[(size_t)b * 393216 + rem] = float2{s0, s1};
}

extern "C" void kernel_launch(void* const* d_in, const int* in_sizes, int n_in,
                              void* d_out, int out_size, void* d_ws, size_t ws_size,
                              hipStream_t stream) {
  const float* X  = (const float*)d_in[0];
  const float* Wq = (const float*)d_in[1];
  const float* Wk = (const float*)d_in[2];
  const float* Wv = (const float*)d_in[3];
  const float* Wr = (const float*)d_in[4];

  char* ws = (char*)d_ws;
  ushort_t* Mw  = (ushort_t*)(ws);
  ushort_t* Qw  = (ushort_t*)(ws + 2359296);     // Kw = Qw + 4,194,304 shorts
  ushort_t* Kw  = (ushort_t*)(ws + 10747904);
  ushort_t* UT  = (ushort_t*)(ws + 19136512);
  __hip_bfloat16* Ow = (__hip_bfloat16*)(ws + 69468160);
  ushort_t* Xw  = (ushort_t*)(ws + 69468160);    // aliases Ow (dead until attn)
  ushort_t* Wqw = (ushort_t*)(ws + 75759616);    // aliases Ow; Wkw = Wqw + 147,456
  ushort_t* Wkw = (ushort_t*)(ws + 76054528);

  cvt_all_kernel<<<dim3(3360), 256, 0, stream>>>(X, Wq, Wk, Xw, Wqw, Wkw);
  prep_m_kernel<<<dim3(6, 6, 8), 256, 0, stream>>>(Wr, Wv, Mw);

  gemm_kernel<0><<<dim3(64, 3, 2), 256, 0, stream>>>(Xw, Wqw, Qw);   // z=0:Q, z=1:K
  gemm_kernel<1><<<dim3(3, 16, 32), 256, 0, stream>>>(Mw, Xw, UT);

  attn_pv_kernel<<<dim3(512), 512, 0, stream>>>(Qw, Kw, UT, Ow);
  reduce_kernel<<<dim3(6144), 256, 0, stream>>>((const uint_t*)Ow, (float2*)d_out);
}